// Round 4
// baseline (524.841 us; speedup 1.0000x reference)
//
#include <hip/hip_runtime.h>
#include <math.h>

#define BLOCK 256
#define NPOS 64           // positions per block
#define C_IN 72
#define CHUNK 24          // K-chunk: 3 vmcnt waits per conv, 24 loads in flight
#define ROW_STRIDE 99     // 15 box + 80 exp + 3 partial + 1 inv = 99 slots

__device__ __forceinline__ float sigf(float x) {
    return __builtin_amdgcn_rcpf(1.0f + __expf(-x));
}

// Chunked 1x1-conv: NO output channels for one position.
// K read in chunks of CHUNK (coalesced, each element loaded exactly once),
// accumulators persistent in registers (o-loop fully unrolled, const indices).
// Weight/bias addresses are wave-uniform -> s_load + SGPR operands of v_fmac.
// Live set: NO acc + CHUNK in + addressing -> <=85 VGPR for NO<=27.
template<int NO>
__device__ __forceinline__ void conv_nk(const float* __restrict__ src, int HW,
                                        const float* __restrict__ w,     // + o_beg*C_IN
                                        const float* __restrict__ bias,  // + o_beg
                                        float* acc)
{
#pragma unroll
    for (int o = 0; o < NO; ++o) acc[o] = bias[o];
    for (int cc = 0; cc < C_IN; cc += CHUNK) {   // rolled: 3 iterations, small I$
        float inx[CHUNK];
#pragma unroll
        for (int j = 0; j < CHUNK; ++j) inx[j] = src[(cc + j) * HW];
#pragma unroll
        for (int o = 0; o < NO; ++o) {
            const float* wr = w + o * C_IN + cc;
#pragma unroll
            for (int j = 0; j < CHUNK; ++j) acc[o] += inx[j] * wr[j];
        }
    }
}

__global__ void __launch_bounds__(BLOCK, 6)
yolo_head_kernel(const float* __restrict__ fr0, const float* __restrict__ fo0, const float* __restrict__ fc0,
                 const float* __restrict__ fr1, const float* __restrict__ fo1, const float* __restrict__ fc1,
                 const float* __restrict__ w_reg, const float* __restrict__ b_reg,
                 const float* __restrict__ w_obj, const float* __restrict__ b_obj,
                 const float* __restrict__ w_cls, const float* __restrict__ b_cls,
                 float* __restrict__ out)
{
    __shared__ float lds[NPOS * ROW_STRIDE];
    __shared__ int   itab[255];          // writer decode table: (lds_idx<<1) | mul_flag
    const int bid  = blockIdx.x;
    const int tid  = threadIdx.x;
    const int lane = tid & 63;
    const int grp  = tid >> 6;

    // writer decode table, built once per block (before first barrier)
    if (tid < 255) {
        int k  = tid;
        int a  = (k >= 85) + (k >= 170);
        int kk = k - a * 85;
        int idx = (kk < 5) ? (a * 5 + kk) : (kk + 10);
        itab[k] = (idx << 1) | (kk >= 5);
    }

    // runtime level config (single code copy -> fits I$)
    int lvl, b, pos0, HW, W, LO;
    const float *fr, *fo, *fc;
    if (bid < 1600) {          // level 0: 25 blocks/image * 64 pos (exact)
        lvl = 0; b = bid / 25; pos0 = (bid % 25) * NPOS;
        HW = 1600; W = 40; LO = 0; fr = fr0; fo = fo0; fc = fc0;
    } else {                   // level 1: 7 blocks/image (6*64 + 16-tail)
        int t = bid - 1600;
        lvl = 1; b = t / 7; pos0 = (t % 7) * NPOS;
        HW = 400; W = 20; LO = 4800; fr = fr1; fo = fo1; fc = fc1;
    }
    const float STRIDE = lvl ? 32.0f : 16.0f;

    const int active = (HW - pos0 < NPOS) ? (HW - pos0) : NPOS;
    const int pos    = pos0 + lane;
    const int posc   = (pos < HW) ? pos : (HW - 1);   // clamp masked tail lanes
    const int fbase  = b * C_IN * HW + posc;
    float* row = lds + lane * ROW_STRIDE;

    if (grp == 0) {
        // ---- reg conv (12) + obj conv (3) + box decode ----
        float r[12], ob[3];
        conv_nk<12>(fr + fbase, HW, w_reg, b_reg, r);
        conv_nk<3>(fo + fbase, HW, w_obj, b_obj, ob);

        const int gyi = lvl ? (posc / 20) : (posc / 40);   // const-div magic-mul
        const float gx = (float)(posc - gyi * W);
        const float gy = (float)gyi;
        float A[6];
        if (lvl == 0) { A[0]=12.64f;  A[1]=19.39f;  A[2]=37.88f;  A[3]=51.48f;  A[4]=55.71f;  A[5]=138.31f; }
        else          { A[0]=126.91f; A[1]=78.23f;  A[2]=131.57f; A[3]=214.55f; A[4]=279.92f; A[5]=258.87f; }
#pragma unroll
        for (int a = 0; a < 3; ++a) {
            float x  = (sigf(r[4*a + 0]) * 2.0f - 0.5f + gx) * STRIDE;
            float y  = (sigf(r[4*a + 1]) * 2.0f - 0.5f + gy) * STRIDE;
            float tw = sigf(r[4*a + 2]) * 2.0f;
            float th = sigf(r[4*a + 3]) * 2.0f;
            row[a*5 + 0] = x;
            row[a*5 + 1] = y;
            row[a*5 + 2] = tw * tw * A[2*a + 0];
            row[a*5 + 3] = th * th * A[2*a + 1];
            row[a*5 + 4] = sigf(ob[a]);
        }
    } else {
        // ---- cls conv: 3 waves, 27 channels each, o_beg in {0,27,53}.
        // Channel 53 computed by grp2 AND grp3 (identical value, benign race);
        // its exp is double-counted in the partials and subtracted below.
        const int o_beg = (grp == 1) ? 0 : (grp == 2) ? 27 : 53;
        float acc[27];
        conv_nk<27>(fc + fbase, HW, w_cls + o_beg * C_IN, b_cls + o_beg, acc);
        float s = 0.f;
#pragma unroll
        for (int o = 0; o < 27; ++o) {
            // softmax shift-invariant; logits O(1), exp cannot overflow fp32
            float e = __expf(acc[o]);
            s += e;
            row[15 + o_beg + o] = e;
        }
        row[94 + grp] = s;   // partials in slots 95..97
    }
    __syncthreads();

    if (tid < NPOS) {
        float* rr = lds + tid * ROW_STRIDE;
        // subtract the double-counted exp(ch53) (slot 15+53)
        rr[98] = __builtin_amdgcn_rcpf(rr[95] + rr[96] + rr[97] - rr[68]);
    }
    __syncthreads();

    // ---- cooperative coalesced writer: active*255 contiguous floats, float4 ----
    const int limit = active * 255;                        // 16320 or 4080, %4==0
    float* outp = out + (b * 510000 + LO * 85 + pos0 * 255);  // 16B-aligned

    for (int f0 = tid * 4; f0 < limit; f0 += BLOCK * 4) {
        float4 v4;
        float* pv = &v4.x;
#pragma unroll
        for (int j = 0; j < 4; ++j) {
            int ff = f0 + j;
            int op = ff / 255;             // magic-mul
            int k  = ff - op * 255;
            int t  = itab[k];
            const float* rw = lds + op * ROW_STRIDE;
            float v = rw[t >> 1];
            if (t & 1) v *= rw[98];
            pv[j] = v;
        }
        *reinterpret_cast<float4*>(outp + f0) = v4;
    }
}

extern "C" void kernel_launch(void* const* d_in, const int* in_sizes, int n_in,
                              void* d_out, int out_size, void* d_ws, size_t ws_size,
                              hipStream_t stream) {
    (void)in_sizes; (void)n_in; (void)d_ws; (void)ws_size; (void)out_size;
    const float* fr0  = (const float*)d_in[0];
    const float* fo0  = (const float*)d_in[1];
    const float* fc0  = (const float*)d_in[2];
    const float* fr1  = (const float*)d_in[3];
    const float* fo1  = (const float*)d_in[4];
    const float* fc1  = (const float*)d_in[5];
    const float* wreg = (const float*)d_in[6];
    const float* breg = (const float*)d_in[7];
    const float* wobj = (const float*)d_in[8];
    const float* bobj = (const float*)d_in[9];
    const float* wcls = (const float*)d_in[10];
    const float* bcls = (const float*)d_in[11];
    float* out = (float*)d_out;

    // 1600 level-0 blocks + 64*7 = 448 level-1 blocks
    yolo_head_kernel<<<2048, BLOCK, 0, stream>>>(
        fr0, fo0, fc0, fr1, fo1, fc1,
        wreg, breg, wobj, bobj, wcls, bcls, out);
}

// Round 5
// 257.630 us; speedup vs baseline: 2.0372x; 2.0372x over previous
//
#include <hip/hip_runtime.h>
#include <math.h>

#define BLOCK 256
#define NPOS 64
#define C_IN 72
#define AST 100        // A-row stride in shorts (per pos); pad c to 96, slots 96..99 unused
#define RST 100        // row-buffer stride in floats: 0..14 box, 16..95 exp, 99 inv

typedef short short8  __attribute__((ext_vector_type(8)));
typedef float floatx4 __attribute__((ext_vector_type(4)));

__device__ __forceinline__ unsigned short f2bf(float f) {   // RNE float->bf16
    unsigned u = __float_as_uint(f);
    u += 0x7FFFu + ((u >> 16) & 1u);
    return (unsigned short)(u >> 16);
}
__device__ __forceinline__ float sigf(float x) {
    return __builtin_amdgcn_rcpf(1.0f + __expf(-x));
}

__global__ void __launch_bounds__(BLOCK, 4)
yolo_head_kernel(const float* __restrict__ fr0, const float* __restrict__ fo0, const float* __restrict__ fc0,
                 const float* __restrict__ fr1, const float* __restrict__ fo1, const float* __restrict__ fc1,
                 const float* __restrict__ w_reg, const float* __restrict__ b_reg,
                 const float* __restrict__ w_obj, const float* __restrict__ b_obj,
                 const float* __restrict__ w_cls, const float* __restrict__ b_cls,
                 float* __restrict__ out)
{
    // A-buffers [3 tensors][64 pos][100 c] bf16 = 38400 B; row buffer (25600 B)
    // aliases the same memory AFTER the post-MFMA barrier.
    __shared__ __align__(16) short sA[3 * NPOS * AST];
    __shared__ int itab[255];
    float* row = (float*)sA;

    const int bid  = blockIdx.x;
    const int tid  = threadIdx.x;
    const int lane = tid & 63;
    const int wv   = tid >> 6;
    const int m    = lane & 15;    // MFMA row/col-in-tile index
    const int quad = lane >> 4;

    // writer decode table: (row_slot<<1) | softmax_flag
    if (tid < 255) {
        int k  = tid;
        int a  = (k >= 85) + (k >= 170);
        int kk = k - a * 85;
        int idx = (kk < 5) ? (a * 5 + kk) : (kk + 11);   // box slot or exp slot 16+(kk-5)
        itab[k] = (idx << 1) | (kk >= 5);
    }

    // runtime level config (single code copy)
    int lvl, b, pos0, HW, W, LO;
    const float *fr, *fo, *fc;
    if (bid < 1600) {          // level 0: 25 blocks/image * 64 pos (exact)
        lvl = 0; b = bid / 25; pos0 = (bid % 25) * NPOS;
        HW = 1600; W = 40; LO = 0; fr = fr0; fo = fo0; fc = fc0;
    } else {                   // level 1: 7 blocks/image (6*64 + 16-tail)
        int t = bid - 1600;
        lvl = 1; b = t / 7; pos0 = (t % 7) * NPOS;
        HW = 400; W = 20; LO = 4800; fr = fr1; fo = fo1; fc = fc1;
    }
    const float STRIDE = lvl ? 32.0f : 16.0f;
    const int active = (HW - pos0 < NPOS) ? (HW - pos0) : NPOS;
    const int pos    = pos0 + lane;
    const int posc   = (pos < HW) ? pos : (HW - 1);

    // ---- stage X -> LDS bf16, layout [t][pos][c] (transposed from global) ----
    // thread (wv,lane): loads channel pair (c0,c0+1) for position `lane`;
    // 54 independent coalesced loads per thread -> deep MLP, single wait region.
    {
        int* sAi = (int*)sA;
        const float* srcs[3] = {fr, fo, fc};
#pragma unroll
        for (int t = 0; t < 3; ++t) {
            const float* sp = srcs[t] + b * C_IN * HW + posc;
            int* dp = sAi + t * (NPOS * AST / 2) + lane * (AST / 2);
#pragma unroll
            for (int i = 0; i < 9; ++i) {
                int c0 = wv * 2 + i * 8;                 // covers even 0..70
                float v0 = sp[c0 * HW];
                float v1 = sp[(c0 + 1) * HW];
                dp[c0 >> 1] = (int)f2bf(v0) | ((int)f2bf(v1) << 16);
            }
        }
        // zero-pad c 72..95 (int slots 36..47 per pos)
        for (int i = tid; i < 3 * NPOS * 12; i += BLOCK) {
            int t = i / (NPOS * 12), r = i - t * (NPOS * 12);
            int p = r / 12, s = r - p * 12;
            sAi[t * (NPOS * AST / 2) + p * (AST / 2) + 36 + s] = 0;
        }
    }
    __syncthreads();

    // ---- MFMA phase: wave wv owns position slab mt = wv (16 pos), all 95 och ----
    const int mt = wv;
    auto afrag = [&](int t, int kc) -> short8 {
        // A[m=lane&15][k=quad*8+j]; LDS [pos][c] -> 8 consecutive shorts, 16B aligned
        return *reinterpret_cast<const short8*>(
            sA + t * (NPOS * AST) + (mt * 16 + m) * AST + kc * 32 + quad * 8);
    };
    auto bfrag = [&](const float* wrow, int kc, bool valid) -> short8 {
        // B[n=lane&15][k=quad*8+j]; per-lane gather of 8 consecutive fp32 weights
        short8 r = {0, 0, 0, 0, 0, 0, 0, 0};
        if (valid && !(kc == 2 && quad != 0)) {          // k>=72 is zero padding
            const float4* p = (const float4*)(wrow + kc * 32 + quad * 8);
            float4 f0 = p[0], f1 = p[1];
            r[0] = (short)f2bf(f0.x); r[1] = (short)f2bf(f0.y);
            r[2] = (short)f2bf(f0.z); r[3] = (short)f2bf(f0.w);
            r[4] = (short)f2bf(f1.x); r[5] = (short)f2bf(f1.y);
            r[6] = (short)f2bf(f1.z); r[7] = (short)f2bf(f1.w);
        }
        return r;
    };

    floatx4 accR = {0, 0, 0, 0}, accO = {0, 0, 0, 0}, accC[5];
    {   // reg conv: och = m (valid < 12), A from fr (t=0)
        const float* wrow = w_reg + m * C_IN;
        bool v = (m < 12);
#pragma unroll
        for (int kc = 0; kc < 3; ++kc)
            accR = __builtin_amdgcn_mfma_f32_16x16x32_bf16(afrag(0, kc), bfrag(wrow, kc, v), accR, 0, 0, 0);
    }
    {   // obj conv: och = m (valid < 3), A from fo (t=1)
        const float* wrow = w_obj + m * C_IN;
        bool v = (m < 3);
#pragma unroll
        for (int kc = 0; kc < 3; ++kc)
            accO = __builtin_amdgcn_mfma_f32_16x16x32_bf16(afrag(1, kc), bfrag(wrow, kc, v), accO, 0, 0, 0);
    }
#pragma unroll
    for (int nt = 0; nt < 5; ++nt) {   // cls conv: och = nt*16+m (80 = 5 full tiles), A from fc
        const float* wrow = w_cls + (nt * 16 + m) * C_IN;
        floatx4 a4 = {0, 0, 0, 0};
#pragma unroll
        for (int kc = 0; kc < 3; ++kc)
            a4 = __builtin_amdgcn_mfma_f32_16x16x32_bf16(afrag(2, kc), bfrag(wrow, kc, true), a4, 0, 0, 0);
        accC[nt] = a4;
    }

    // all sA reads done -> safe to alias row buffer over it
    __syncthreads();

    // ---- scatter D (+bias) into row buffer; C/D layout: col=lane&15, row=quad*4+i ----
#pragma unroll
    for (int i = 0; i < 4; ++i) {
        int pl = mt * 16 + quad * 4 + i;
        if (m < 12) row[pl * RST + m]      = accR[i] + b_reg[m];
        if (m < 3)  row[pl * RST + 12 + m] = accO[i] + b_obj[m];
    }
#pragma unroll
    for (int nt = 0; nt < 5; ++nt) {
        float bc = b_cls[nt * 16 + m];
#pragma unroll
        for (int i = 0; i < 4; ++i) {
            int pl = mt * 16 + quad * 4 + i;
            // softmax shift-invariant; logits O(1), exp cannot overflow fp32
            row[pl * RST + 16 + nt * 16 + m] = __expf(accC[nt][i] + bc);
        }
    }
    __syncthreads();

    // ---- per-position: softmax denom + box decode (in-place slots 0..14) ----
    if (tid < NPOS) {
        float* rr = row + tid * RST;
        float s = 0.f;
#pragma unroll
        for (int i2 = 0; i2 < 20; ++i2) {
            floatx4 e4 = *reinterpret_cast<const floatx4*>(rr + 16 + i2 * 4);  // 16B aligned
            s += (e4[0] + e4[1]) + (e4[2] + e4[3]);
        }
        rr[99] = __builtin_amdgcn_rcpf(s);

        float r12[12], ob3[3];
#pragma unroll
        for (int j = 0; j < 12; ++j) r12[j] = rr[j];
#pragma unroll
        for (int a = 0; a < 3; ++a) ob3[a] = rr[12 + a];

        int pg = pos0 + tid; if (pg >= HW) pg = HW - 1;
        const int gyi = lvl ? (pg / 20) : (pg / 40);
        const float gx = (float)(pg - gyi * W);
        const float gy = (float)gyi;
        float A[6];
        if (lvl == 0) { A[0]=12.64f;  A[1]=19.39f;  A[2]=37.88f;  A[3]=51.48f;  A[4]=55.71f;  A[5]=138.31f; }
        else          { A[0]=126.91f; A[1]=78.23f;  A[2]=131.57f; A[3]=214.55f; A[4]=279.92f; A[5]=258.87f; }
#pragma unroll
        for (int a = 0; a < 3; ++a) {
            float x  = (sigf(r12[4*a + 0]) * 2.0f - 0.5f + gx) * STRIDE;
            float y  = (sigf(r12[4*a + 1]) * 2.0f - 0.5f + gy) * STRIDE;
            float tw = sigf(r12[4*a + 2]) * 2.0f;
            float th = sigf(r12[4*a + 3]) * 2.0f;
            rr[a*5 + 0] = x;
            rr[a*5 + 1] = y;
            rr[a*5 + 2] = tw * tw * A[2*a + 0];
            rr[a*5 + 3] = th * th * A[2*a + 1];
            rr[a*5 + 4] = sigf(ob3[a]);
        }
    }
    __syncthreads();

    // ---- cooperative coalesced writer: active*255 contiguous floats, float4 ----
    const int limit = active * 255;                      // 16320 or 4080, %4==0
    float* outp = out + (b * 510000 + LO * 85 + pos0 * 255);   // 16B-aligned

    for (int f0 = tid * 4; f0 < limit; f0 += BLOCK * 4) {
        float4 v4;
        float* pv = &v4.x;
#pragma unroll
        for (int j = 0; j < 4; ++j) {
            int ff = f0 + j;
            int op = ff / 255;            // magic-mul
            int k  = ff - op * 255;
            int t  = itab[k];
            const float* rw = row + op * RST;
            float v = rw[t >> 1];
            if (t & 1) v *= rw[99];
            pv[j] = v;
        }
        *reinterpret_cast<float4*>(outp + f0) = v4;
    }
}

extern "C" void kernel_launch(void* const* d_in, const int* in_sizes, int n_in,
                              void* d_out, int out_size, void* d_ws, size_t ws_size,
                              hipStream_t stream) {
    (void)in_sizes; (void)n_in; (void)d_ws; (void)ws_size; (void)out_size;
    const float* fr0  = (const float*)d_in[0];
    const float* fo0  = (const float*)d_in[1];
    const float* fc0  = (const float*)d_in[2];
    const float* fr1  = (const float*)d_in[3];
    const float* fo1  = (const float*)d_in[4];
    const float* fc1  = (const float*)d_in[5];
    const float* wreg = (const float*)d_in[6];
    const float* breg = (const float*)d_in[7];
    const float* wobj = (const float*)d_in[8];
    const float* bobj = (const float*)d_in[9];
    const float* wcls = (const float*)d_in[10];
    const float* bcls = (const float*)d_in[11];
    float* out = (float*)d_out;

    // 1600 level-0 blocks + 64*7 = 448 level-1 blocks
    yolo_head_kernel<<<2048, BLOCK, 0, stream>>>(
        fr0, fo0, fc0, fr1, fo1, fc1,
        wreg, breg, wobj, bobj, wcls, bcls, out);
}

// Round 6
// 253.281 us; speedup vs baseline: 2.0722x; 1.0172x over previous
//
#include <hip/hip_runtime.h>
#include <math.h>

#define BLOCK 256
#define NPOS 64
#define C_IN 72
#define AST 100        // A-row stride in shorts (per pos); pad c to 96, slots 96..99 unused
#define RST 100        // row-buffer stride in floats: 0..14 box, 16..95 exp, 99 inv
#define NFRAG 21       // 7 n-tiles x 3 k-chunks

typedef short short8  __attribute__((ext_vector_type(8)));
typedef float floatx4 __attribute__((ext_vector_type(4)));

__device__ __forceinline__ unsigned short f2bf(float f) {   // RNE float->bf16
    unsigned u = __float_as_uint(f);
    u += 0x7FFFu + ((u >> 16) & 1u);
    return (unsigned short)(u >> 16);
}
__device__ __forceinline__ float sigf(float x) {
    return __builtin_amdgcn_rcpf(1.0f + __expf(-x));
}

// ---- kernel 1: pre-pack all B fragments (bf16, MFMA B-operand layout) ----
// frag fi = tile*3+kc; lane holds B[n=lane&15][k=quad*8+j] for k-chunk kc.
// Tiles: 0=reg(12 valid), 1=obj(3 valid), 2..6=cls rows nt*16+m. k>=72 zero-pad.
__global__ void __launch_bounds__(BLOCK)
build_bfrags_kernel(const float* __restrict__ w_reg,
                    const float* __restrict__ w_obj,
                    const float* __restrict__ w_cls,
                    short8* __restrict__ frags)
{
    int idx = blockIdx.x * BLOCK + threadIdx.x;
    if (idx >= NFRAG * 64) return;
    int lane = idx & 63;
    int fi   = idx >> 6;
    int tile = fi / 3, kc = fi - tile * 3;
    int m = lane & 15, quad = lane >> 4;
    const float* wrow;
    bool valid = true;
    if (tile == 0)      { wrow = w_reg + m * C_IN; valid = (m < 12); }
    else if (tile == 1) { wrow = w_obj + m * C_IN; valid = (m < 3); }
    else                { wrow = w_cls + ((tile - 2) * 16 + m) * C_IN; }
    short8 r = {0, 0, 0, 0, 0, 0, 0, 0};
    if (valid && !(kc == 2 && quad != 0)) {
        const float* p = wrow + kc * 32 + quad * 8;
#pragma unroll
        for (int j = 0; j < 8; ++j) r[j] = (short)f2bf(p[j]);
    }
    frags[fi * 64 + lane] = r;
}

// ---- kernel 2: main fused head ----
__global__ void __launch_bounds__(BLOCK, 4)
yolo_head_kernel(const float* __restrict__ fr0, const float* __restrict__ fo0, const float* __restrict__ fc0,
                 const float* __restrict__ fr1, const float* __restrict__ fo1, const float* __restrict__ fc1,
                 const float* __restrict__ b_reg, const float* __restrict__ b_obj,
                 const float* __restrict__ b_cls,
                 const short8* __restrict__ wfrag,
                 float* __restrict__ out)
{
    // A-buffers [3 tensors][64 pos][100 c] bf16 = 38400 B; row buffer (25600 B)
    // aliases the same memory AFTER the post-MFMA barrier.
    __shared__ __align__(16) short sA[3 * NPOS * AST];
    __shared__ int itab[255];
    float* row = (float*)sA;

    const int bid  = blockIdx.x;
    const int tid  = threadIdx.x;
    const int lane = tid & 63;
    const int wv   = tid >> 6;
    const int m    = lane & 15;
    const int quad = lane >> 4;

    // writer decode table: (row_slot<<1) | softmax_flag
    if (tid < 255) {
        int k  = tid;
        int a  = (k >= 85) + (k >= 170);
        int kk = k - a * 85;
        int idx = (kk < 5) ? (a * 5 + kk) : (kk + 11);   // box slot or exp slot 16+(kk-5)
        itab[k] = (idx << 1) | (kk >= 5);
    }

    // runtime level config (single code copy)
    int lvl, b, pos0, HW, W, LO;
    const float *fr, *fo, *fc;
    if (bid < 1600) {          // level 0: 25 blocks/image * 64 pos (exact)
        lvl = 0; b = bid / 25; pos0 = (bid % 25) * NPOS;
        HW = 1600; W = 40; LO = 0; fr = fr0; fo = fo0; fc = fc0;
    } else {                   // level 1: 7 blocks/image (6*64 + 16-tail)
        int t = bid - 1600;
        lvl = 1; b = t / 7; pos0 = (t % 7) * NPOS;
        HW = 400; W = 20; LO = 4800; fr = fr1; fo = fo1; fc = fc1;
    }
    const float STRIDE = lvl ? 32.0f : 16.0f;
    const int active = (HW - pos0 < NPOS) ? (HW - pos0) : NPOS;
    const int pos    = pos0 + lane;
    const int posc   = (pos < HW) ? pos : (HW - 1);

    // ---- stage X -> LDS bf16, layout [t][pos][c] ----
    {
        int* sAi = (int*)sA;
        const float* srcs[3] = {fr, fo, fc};
#pragma unroll
        for (int t = 0; t < 3; ++t) {
            const float* sp = srcs[t] + b * C_IN * HW + posc;
            int* dp = sAi + t * (NPOS * AST / 2) + lane * (AST / 2);
#pragma unroll
            for (int i = 0; i < 9; ++i) {
                int c0 = wv * 2 + i * 8;                 // covers even 0..70
                float v0 = sp[c0 * HW];
                float v1 = sp[(c0 + 1) * HW];
                dp[c0 >> 1] = (int)f2bf(v0) | ((int)f2bf(v1) << 16);
            }
        }
        // zero-pad c 72..95 (int slots 36..47 per pos)
        for (int i = tid; i < 3 * NPOS * 12; i += BLOCK) {
            int t = i / (NPOS * 12), r = i - t * (NPOS * 12);
            int p = r / 12, s = r - p * 12;
            sAi[t * (NPOS * AST / 2) + p * (AST / 2) + 36 + s] = 0;
        }
    }

    // ---- preload ALL pre-packed B fragments (independent coalesced 16B loads;
    // latency hides under the staging barrier). ~84 VGPRs, budget 128. ----
    short8 bf[NFRAG];
#pragma unroll
    for (int i = 0; i < NFRAG; ++i) bf[i] = wfrag[i * 64 + lane];

    __syncthreads();

    // ---- MFMA phase: wave wv owns position slab (16 pos), all 95 och ----
    const int mt = wv;
    auto afrag = [&](int t, int kc) -> short8 {
        // A[m=lane&15][k=quad*8+j]; 8 consecutive shorts, 16B aligned
        return *reinterpret_cast<const short8*>(
            sA + t * (NPOS * AST) + (mt * 16 + m) * AST + kc * 32 + quad * 8);
    };

    floatx4 accR = {0, 0, 0, 0}, accO = {0, 0, 0, 0}, accC[5];
#pragma unroll
    for (int kc = 0; kc < 3; ++kc)
        accR = __builtin_amdgcn_mfma_f32_16x16x32_bf16(afrag(0, kc), bf[0 * 3 + kc], accR, 0, 0, 0);
#pragma unroll
    for (int kc = 0; kc < 3; ++kc)
        accO = __builtin_amdgcn_mfma_f32_16x16x32_bf16(afrag(1, kc), bf[1 * 3 + kc], accO, 0, 0, 0);
#pragma unroll
    for (int nt = 0; nt < 5; ++nt) {
        floatx4 a4 = {0, 0, 0, 0};
#pragma unroll
        for (int kc = 0; kc < 3; ++kc)
            a4 = __builtin_amdgcn_mfma_f32_16x16x32_bf16(afrag(2, kc), bf[(nt + 2) * 3 + kc], a4, 0, 0, 0);
        accC[nt] = a4;
    }

    // all sA reads done -> safe to alias row buffer over it
    __syncthreads();

    // ---- scatter D (+bias) into row buffer; C/D layout: col=lane&15, row=quad*4+i ----
#pragma unroll
    for (int i = 0; i < 4; ++i) {
        int pl = mt * 16 + quad * 4 + i;
        if (m < 12) row[pl * RST + m]      = accR[i] + b_reg[m];
        if (m < 3)  row[pl * RST + 12 + m] = accO[i] + b_obj[m];
    }
#pragma unroll
    for (int nt = 0; nt < 5; ++nt) {
        float bc = b_cls[nt * 16 + m];
#pragma unroll
        for (int i = 0; i < 4; ++i) {
            int pl = mt * 16 + quad * 4 + i;
            // softmax shift-invariant; logits O(1), exp cannot overflow fp32
            row[pl * RST + 16 + nt * 16 + m] = __expf(accC[nt][i] + bc);
        }
    }
    __syncthreads();

    // ---- per-position: softmax denom + box decode (in-place slots 0..14) ----
    if (tid < NPOS) {
        float* rr = row + tid * RST;
        float s = 0.f;
#pragma unroll
        for (int i2 = 0; i2 < 20; ++i2) {
            floatx4 e4 = *reinterpret_cast<const floatx4*>(rr + 16 + i2 * 4);
            s += (e4[0] + e4[1]) + (e4[2] + e4[3]);
        }
        rr[99] = __builtin_amdgcn_rcpf(s);

        float r12[12], ob3[3];
#pragma unroll
        for (int j = 0; j < 12; ++j) r12[j] = rr[j];
#pragma unroll
        for (int a = 0; a < 3; ++a) ob3[a] = rr[12 + a];

        int pg = pos0 + tid; if (pg >= HW) pg = HW - 1;
        const int gyi = lvl ? (pg / 20) : (pg / 40);
        const float gx = (float)(pg - gyi * W);
        const float gy = (float)gyi;
        float A[6];
        if (lvl == 0) { A[0]=12.64f;  A[1]=19.39f;  A[2]=37.88f;  A[3]=51.48f;  A[4]=55.71f;  A[5]=138.31f; }
        else          { A[0]=126.91f; A[1]=78.23f;  A[2]=131.57f; A[3]=214.55f; A[4]=279.92f; A[5]=258.87f; }
#pragma unroll
        for (int a = 0; a < 3; ++a) {
            float x  = (sigf(r12[4*a + 0]) * 2.0f - 0.5f + gx) * STRIDE;
            float y  = (sigf(r12[4*a + 1]) * 2.0f - 0.5f + gy) * STRIDE;
            float tw = sigf(r12[4*a + 2]) * 2.0f;
            float th = sigf(r12[4*a + 3]) * 2.0f;
            rr[a*5 + 0] = x;
            rr[a*5 + 1] = y;
            rr[a*5 + 2] = tw * tw * A[2*a + 0];
            rr[a*5 + 3] = th * th * A[2*a + 1];
            rr[a*5 + 4] = sigf(ob3[a]);
        }
    }
    __syncthreads();

    // ---- cooperative coalesced writer: active*255 contiguous floats, float4 ----
    const int limit = active * 255;                      // 16320 or 4080, %4==0
    float* outp = out + (b * 510000 + LO * 85 + pos0 * 255);   // 16B-aligned

    for (int f0 = tid * 4; f0 < limit; f0 += BLOCK * 4) {
        float4 v4;
        float* pv = &v4.x;
#pragma unroll
        for (int j = 0; j < 4; ++j) {
            int ff = f0 + j;
            int op = ff / 255;            // magic-mul
            int k  = ff - op * 255;
            int t  = itab[k];
            const float* rw = row + op * RST;
            float v = rw[t >> 1];
            if (t & 1) v *= rw[99];
            pv[j] = v;
        }
        *reinterpret_cast<float4*>(outp + f0) = v4;
    }
}

extern "C" void kernel_launch(void* const* d_in, const int* in_sizes, int n_in,
                              void* d_out, int out_size, void* d_ws, size_t ws_size,
                              hipStream_t stream) {
    (void)in_sizes; (void)n_in; (void)ws_size; (void)out_size;
    const float* fr0  = (const float*)d_in[0];
    const float* fo0  = (const float*)d_in[1];
    const float* fc0  = (const float*)d_in[2];
    const float* fr1  = (const float*)d_in[3];
    const float* fo1  = (const float*)d_in[4];
    const float* fc1  = (const float*)d_in[5];
    const float* wreg = (const float*)d_in[6];
    const float* breg = (const float*)d_in[7];
    const float* wobj = (const float*)d_in[8];
    const float* bobj = (const float*)d_in[9];
    const float* wcls = (const float*)d_in[10];
    const float* bcls = (const float*)d_in[11];
    float* out = (float*)d_out;
    short8* frags = (short8*)d_ws;    // 21*64*16 = 21504 B

    // d_ws is re-poisoned before every call -> rebuild fragments every call
    build_bfrags_kernel<<<6, BLOCK, 0, stream>>>(wreg, wobj, wcls, frags);

    // 1600 level-0 blocks + 64*7 = 448 level-1 blocks
    yolo_head_kernel<<<2048, BLOCK, 0, stream>>>(
        fr0, fo0, fc0, fr1, fo1, fc1,
        breg, bobj, bcls, frags, out);
}

// Round 7
// 248.864 us; speedup vs baseline: 2.1090x; 1.0178x over previous
//
#include <hip/hip_runtime.h>
#include <math.h>

#define BLOCK 256
#define NPOS 64
#define C_IN 72
#define AST 102        // shorts per pos; 51 ints -> odd stride -> conflict-free staging writes
#define ASTI 51
#define TSZ (NPOS * AST)     // shorts per tensor buffer
#define RST 100        // row-buffer stride (floats): 0..14 box, 15..94 exp, 95 inv
#define NFRAG 21       // 7 n-tiles x 3 k-chunks

typedef short short8  __attribute__((ext_vector_type(8)));
typedef float floatx4 __attribute__((ext_vector_type(4)));

__device__ __forceinline__ unsigned short f2bf(float f) {   // RNE float->bf16
    unsigned u = __float_as_uint(f);
    u += 0x7FFFu + ((u >> 16) & 1u);
    return (unsigned short)(u >> 16);
}
__device__ __forceinline__ float sigf(float x) {
    return __builtin_amdgcn_rcpf(1.0f + __expf(-x));
}

// ---- kernel 1: pre-pack all B fragments (bf16, MFMA B-operand layout) ----
__global__ void __launch_bounds__(BLOCK)
build_bfrags_kernel(const float* __restrict__ w_reg,
                    const float* __restrict__ w_obj,
                    const float* __restrict__ w_cls,
                    short8* __restrict__ frags)
{
    int idx = blockIdx.x * BLOCK + threadIdx.x;
    if (idx >= NFRAG * 64) return;
    int lane = idx & 63;
    int fi   = idx >> 6;
    int tile = fi / 3, kc = fi - tile * 3;
    int m = lane & 15, quad = lane >> 4;
    const float* wrow;
    bool valid = true;
    if (tile == 0)      { wrow = w_reg + m * C_IN; valid = (m < 12); }
    else if (tile == 1) { wrow = w_obj + m * C_IN; valid = (m < 3); }
    else                { wrow = w_cls + ((tile - 2) * 16 + m) * C_IN; }
    short8 r = {0, 0, 0, 0, 0, 0, 0, 0};
    if (valid && !(kc == 2 && quad != 0)) {
        const float* p = wrow + kc * 32 + quad * 8;
#pragma unroll
        for (int j = 0; j < 8; ++j) r[j] = (short)f2bf(p[j]);
    }
    frags[fi * 64 + lane] = r;
}

// ---- kernel 2: main fused head ----
__global__ void __launch_bounds__(BLOCK, 3)
yolo_head_kernel(const float* __restrict__ fr0, const float* __restrict__ fo0, const float* __restrict__ fc0,
                 const float* __restrict__ fr1, const float* __restrict__ fo1, const float* __restrict__ fc1,
                 const float* __restrict__ b_reg, const float* __restrict__ b_obj,
                 const float* __restrict__ b_cls,
                 const short8* __restrict__ wfrag,
                 float* __restrict__ out)
{
    // A-buffers [3 tensors][64 pos][102 c] bf16 = 39168 B; row buffer (25600 B)
    // aliases the same memory AFTER the post-MFMA barrier.
    __shared__ __align__(16) short sA[3 * TSZ];
    float* row = (float*)sA;

    const int bid  = blockIdx.x;
    const int tid  = threadIdx.x;
    const int lane = tid & 63;
    const int wv   = tid >> 6;
    const int m    = lane & 15;
    const int quad = lane >> 4;

    // runtime level config (single code copy)
    int lvl, b, pos0, HW, W, LO;
    const float *fr, *fo, *fc;
    if (bid < 1600) {          // level 0: 25 blocks/image * 64 pos (exact)
        lvl = 0; b = bid / 25; pos0 = (bid % 25) * NPOS;
        HW = 1600; W = 40; LO = 0; fr = fr0; fo = fo0; fc = fc0;
    } else {                   // level 1: 7 blocks/image (6*64 + 16-tail)
        int t = bid - 1600;
        lvl = 1; b = t / 7; pos0 = (t % 7) * NPOS;
        HW = 400; W = 20; LO = 4800; fr = fr1; fo = fo1; fc = fc1;
    }
    const float STRIDE = lvl ? 32.0f : 16.0f;
    const int active = (HW - pos0 < NPOS) ? (HW - pos0) : NPOS;
    const int pos    = pos0 + lane;
    const int posc   = (pos < HW) ? pos : (HW - 1);

    // ---- issue B-frag loads FIRST (in-order vmcnt: they drain under staging) ----
    short8 bf[NFRAG];
#pragma unroll
    for (int i = 0; i < NFRAG; ++i) bf[i] = wfrag[i * 64 + lane];

    // ---- stage X -> LDS bf16, layout [t][pos][c], odd int-stride (conflict-free) ----
    {
        int* sAi = (int*)sA;
        const float* srcs[3] = {fr, fo, fc};
#pragma unroll
        for (int t = 0; t < 3; ++t) {
            const float* sp = srcs[t] + b * C_IN * HW + posc;
            int* dp = sAi + t * (TSZ / 2) + lane * ASTI;
            float lf[18];
#pragma unroll
            for (int i = 0; i < 9; ++i) {             // 18 independent loads
                int c0 = wv * 2 + i * 8;              // covers even 0..70
                lf[2 * i]     = sp[c0 * HW];
                lf[2 * i + 1] = sp[(c0 + 1) * HW];
            }
#pragma unroll
            for (int i = 0; i < 18; ++i)              // pin: keep all 18 in flight
                asm volatile("" : "+v"(lf[i]));
#pragma unroll
            for (int i = 0; i < 9; ++i) {
                int c0 = wv * 2 + i * 8;
                dp[c0 >> 1] = (int)f2bf(lf[2 * i]) | ((int)f2bf(lf[2 * i + 1]) << 16);
            }
        }
        // pin the B-frags so the compiler can't re-sink the loads to their uses
#pragma unroll
        for (int i = 0; i < NFRAG; ++i)
            asm volatile("" : "+v"(*(floatx4*)&bf[i]));
        // zero-pad c 72..101 (int slots 36..50 per pos)
        for (int i = tid; i < 3 * NPOS * 15; i += BLOCK) {
            int t = i / (NPOS * 15), r = i - t * (NPOS * 15);
            int p = r / 15, s = r - p * 15;
            sAi[t * (TSZ / 2) + p * ASTI + 36 + s] = 0;
        }
    }
    __syncthreads();

    // ---- MFMA phase: wave wv owns position slab (16 pos), all 95 och ----
    const int mt = wv;
    auto afrag = [&](int t, int kc) -> short8 {
        // A[m=lane&15][k=quad*8+j]; 8 consecutive shorts (unaligned b128 OK on gfx950)
        return *reinterpret_cast<const short8*>(
            sA + t * TSZ + (mt * 16 + m) * AST + kc * 32 + quad * 8);
    };

    floatx4 accR = {0, 0, 0, 0}, accO = {0, 0, 0, 0}, accC[5];
#pragma unroll
    for (int kc = 0; kc < 3; ++kc)
        accR = __builtin_amdgcn_mfma_f32_16x16x32_bf16(afrag(0, kc), bf[0 * 3 + kc], accR, 0, 0, 0);
#pragma unroll
    for (int kc = 0; kc < 3; ++kc)
        accO = __builtin_amdgcn_mfma_f32_16x16x32_bf16(afrag(1, kc), bf[1 * 3 + kc], accO, 0, 0, 0);
#pragma unroll
    for (int nt = 0; nt < 5; ++nt) {
        floatx4 a4 = {0, 0, 0, 0};
#pragma unroll
        for (int kc = 0; kc < 3; ++kc)
            a4 = __builtin_amdgcn_mfma_f32_16x16x32_bf16(afrag(2, kc), bf[(nt + 2) * 3 + kc], a4, 0, 0, 0);
        accC[nt] = a4;
    }

    // all sA reads done -> safe to alias row buffer over it
    __syncthreads();

    // ---- scatter D (+bias) into row buffer; C/D layout: col=lane&15, row=quad*4+i ----
#pragma unroll
    for (int i = 0; i < 4; ++i) {
        int pl = mt * 16 + quad * 4 + i;
        if (m < 12) row[pl * RST + m]      = accR[i] + b_reg[m];
        if (m < 3)  row[pl * RST + 12 + m] = accO[i] + b_obj[m];
    }
#pragma unroll
    for (int nt = 0; nt < 5; ++nt) {
        float bc = b_cls[nt * 16 + m];
#pragma unroll
        for (int i = 0; i < 4; ++i) {
            int pl = mt * 16 + quad * 4 + i;
            // softmax shift-invariant; logits O(1), exp cannot overflow fp32
            row[pl * RST + 15 + nt * 16 + m] = __expf(accC[nt][i] + bc);
        }
    }
    __syncthreads();

    // ---- per-position: softmax denom + box decode (in-place slots 0..14) ----
    if (tid < NPOS) {
        float* rr = row + tid * RST;
        // exp slots 15..94: scalars 15,92,93,94 + float4 over 16..91
        float s = rr[15] + rr[92] + rr[93] + rr[94];
#pragma unroll
        for (int i2 = 4; i2 < 23; ++i2) {
            floatx4 e4 = *reinterpret_cast<const floatx4*>(rr + i2 * 4);
            s += (e4[0] + e4[1]) + (e4[2] + e4[3]);
        }
        rr[95] = __builtin_amdgcn_rcpf(s);

        float r12[12], ob3[3];
#pragma unroll
        for (int j = 0; j < 12; ++j) r12[j] = rr[j];
#pragma unroll
        for (int a = 0; a < 3; ++a) ob3[a] = rr[12 + a];

        int pg = pos0 + tid; if (pg >= HW) pg = HW - 1;
        const int gyi = lvl ? (pg / 20) : (pg / 40);
        const float gx = (float)(pg - gyi * W);
        const float gy = (float)gyi;
        float A[6];
        if (lvl == 0) { A[0]=12.64f;  A[1]=19.39f;  A[2]=37.88f;  A[3]=51.48f;  A[4]=55.71f;  A[5]=138.31f; }
        else          { A[0]=126.91f; A[1]=78.23f;  A[2]=131.57f; A[3]=214.55f; A[4]=279.92f; A[5]=258.87f; }
#pragma unroll
        for (int a = 0; a < 3; ++a) {
            float x  = (sigf(r12[4*a + 0]) * 2.0f - 0.5f + gx) * STRIDE;
            float y  = (sigf(r12[4*a + 1]) * 2.0f - 0.5f + gy) * STRIDE;
            float tw = sigf(r12[4*a + 2]) * 2.0f;
            float th = sigf(r12[4*a + 3]) * 2.0f;
            rr[a*5 + 0] = x;
            rr[a*5 + 1] = y;
            rr[a*5 + 2] = tw * tw * A[2*a + 0];
            rr[a*5 + 3] = th * th * A[2*a + 1];
            rr[a*5 + 4] = sigf(ob3[a]);
        }
    }
    __syncthreads();

    // ---- writer: wave-per-position, per-lane slot descriptors precomputed once ----
    // out float f (0..254) of a position: a=f/85, kk=f%85; slot = kk<5 ? a*5+kk : 15+(kk-5)
    int wi[4], wflag[4];
#pragma unroll
    for (int j = 0; j < 4; ++j) {
        int f = lane + 64 * j;
        int k = (f > 254) ? 0 : f;
        int a  = (k >= 85) + (k >= 170);
        int kk = k - a * 85;
        wi[j]    = (kk < 5) ? (a * 5 + kk) : (15 + (kk - 5));
        wflag[j] = (kk >= 5);
    }
    float* outp = out + (b * 510000 + LO * 85 + pos0 * 255);

    for (int p = wv; p < active; p += 4) {
        const float* rr = row + p * RST;
        float inv = rr[95];                         // wave-uniform LDS broadcast
        float* po = outp + p * 255 + lane;
#pragma unroll
        for (int j = 0; j < 4; ++j) {
            if (!(lane == 63 && j == 3)) {          // f=255 masked
                float v = rr[wi[j]];
                if (wflag[j]) v *= inv;
                po[64 * j] = v;                     // consecutive lanes -> coalesced
            }
        }
    }
}

extern "C" void kernel_launch(void* const* d_in, const int* in_sizes, int n_in,
                              void* d_out, int out_size, void* d_ws, size_t ws_size,
                              hipStream_t stream) {
    (void)in_sizes; (void)n_in; (void)ws_size; (void)out_size;
    const float* fr0  = (const float*)d_in[0];
    const float* fo0  = (const float*)d_in[1];
    const float* fc0  = (const float*)d_in[2];
    const float* fr1  = (const float*)d_in[3];
    const float* fo1  = (const float*)d_in[4];
    const float* fc1  = (const float*)d_in[5];
    const float* wreg = (const float*)d_in[6];
    const float* breg = (const float*)d_in[7];
    const float* wobj = (const float*)d_in[8];
    const float* bobj = (const float*)d_in[9];
    const float* wcls = (const float*)d_in[10];
    const float* bcls = (const float*)d_in[11];
    float* out = (float*)d_out;
    short8* frags = (short8*)d_ws;    // 21*64*16 = 21504 B

    // d_ws is re-poisoned before every call -> rebuild fragments every call
    build_bfrags_kernel<<<6, BLOCK, 0, stream>>>(wreg, wobj, wcls, frags);

    // 1600 level-0 blocks + 64*7 = 448 level-1 blocks
    yolo_head_kernel<<<2048, BLOCK, 0, stream>>>(
        fr0, fo0, fc0, fr1, fo1, fc1,
        breg, bobj, bcls, frags, out);
}

// Round 8
// 247.016 us; speedup vs baseline: 2.1247x; 1.0075x over previous
//
#include <hip/hip_runtime.h>
#include <math.h>

#define C_IN 72
#define RST 97         // row-buffer stride (floats): 0..14 box, 15..94 cls(prescaled)
#define NFRAG 21       // 7 n-tiles x 3 k-chunks

typedef short short8  __attribute__((ext_vector_type(8)));
typedef float floatx4 __attribute__((ext_vector_type(4)));

__device__ __forceinline__ unsigned short f2bf(float f) {   // RNE float->bf16
    unsigned u = __float_as_uint(f);
    u += 0x7FFFu + ((u >> 16) & 1u);
    return (unsigned short)(u >> 16);
}
__device__ __forceinline__ float sigf(float x) {
    return __builtin_amdgcn_rcpf(1.0f + __expf(-x));
}

// ---- kernel 1: pre-pack all B fragments (bf16, MFMA B-operand layout) ----
// frag fi = tile*3+kc; lane holds B[n=lane&15][k=quad*8+j].
// Tiles: 0=reg(12 valid), 1=obj(3 valid), 2..6=cls rows nt*16+m. k>=72 zero-pad.
__global__ void __launch_bounds__(256)
build_bfrags_kernel(const float* __restrict__ w_reg,
                    const float* __restrict__ w_obj,
                    const float* __restrict__ w_cls,
                    short8* __restrict__ frags)
{
    int idx = blockIdx.x * 256 + threadIdx.x;
    if (idx >= NFRAG * 64) return;
    int lane = idx & 63;
    int fi   = idx >> 6;
    int tile = fi / 3, kc = fi - tile * 3;
    int m = lane & 15, quad = lane >> 4;
    const float* wrow;
    bool valid = true;
    if (tile == 0)      { wrow = w_reg + m * C_IN; valid = (m < 12); }
    else if (tile == 1) { wrow = w_obj + m * C_IN; valid = (m < 3); }
    else                { wrow = w_cls + ((tile - 2) * 16 + m) * C_IN; }
    short8 r = {0, 0, 0, 0, 0, 0, 0, 0};
    if (valid && !(kc == 2 && quad != 0)) {
        const float* p = wrow + kc * 32 + quad * 8;
#pragma unroll
        for (int j = 0; j < 8; ++j) r[j] = (short)f2bf(p[j]);
    }
    frags[fi * 64 + lane] = r;
}

// ---- kernel 2: main head. ONE WAVE per block, 16 positions, no staging LDS ----
__global__ void __launch_bounds__(64, 4)
yolo_head_kernel(const float* __restrict__ fr0, const float* __restrict__ fo0, const float* __restrict__ fc0,
                 const float* __restrict__ fr1, const float* __restrict__ fo1, const float* __restrict__ fc1,
                 const float* __restrict__ b_reg, const float* __restrict__ b_obj,
                 const float* __restrict__ b_cls,
                 const short8* __restrict__ wfrag,
                 float* __restrict__ out)
{
    __shared__ __align__(16) float row[16 * RST];   // 6208 B only
    const int bid  = blockIdx.x;
    const int lane = threadIdx.x;
    const int m    = lane & 15;
    const int quad = lane >> 4;

    // level mapping: 6400 L0 blocks (100/image) then 1600 L1 blocks (25/image);
    // 16-pos slabs never cross image/level boundaries.
    int lvl, b, pos0, HW, W, LO;
    const float *fr, *fo, *fc;
    if (bid < 6400) {
        lvl = 0; b = bid / 100; pos0 = (bid - b * 100) * 16;
        HW = 1600; W = 40; LO = 0; fr = fr0; fo = fo0; fc = fc0;
    } else {
        int t = bid - 6400;
        lvl = 1; b = t / 25; pos0 = (t - b * 25) * 16;
        HW = 400; W = 20; LO = 4800; fr = fr1; fo = fo1; fc = fc1;
    }
    const float STRIDE = lvl ? 32.0f : 16.0f;

    // ---- A fragments DIRECT from global (no LDS): lane = position m, 8 ch ----
    // A[m=lane&15][k=quad*8+j]; channel k>=72 zero (chunk 2 valid only quad==0).
    const int fbase = b * C_IN * HW + pos0 + m;
    short8 af[3][3];
    const float* srcs[3] = {fr, fo, fc};
#pragma unroll
    for (int t = 0; t < 3; ++t) {
        const float* sp = srcs[t] + fbase;
        float lf[16];
#pragma unroll
        for (int kc = 0; kc < 2; ++kc)
#pragma unroll
            for (int j = 0; j < 8; ++j)
                lf[kc * 8 + j] = sp[(kc * 32 + quad * 8 + j) * HW];
        float l2[8] = {0, 0, 0, 0, 0, 0, 0, 0};
        if (quad == 0) {
#pragma unroll
            for (int j = 0; j < 8; ++j) l2[j] = sp[(64 + j) * HW];
        }
#pragma unroll
        for (int kc = 0; kc < 2; ++kc) {
            short8 r;
#pragma unroll
            for (int j = 0; j < 8; ++j) r[j] = (short)f2bf(lf[kc * 8 + j]);
            af[t][kc] = r;
        }
        short8 r2 = {0, 0, 0, 0, 0, 0, 0, 0};
        if (quad == 0) {
#pragma unroll
            for (int j = 0; j < 8; ++j) r2[j] = (short)f2bf(l2[j]);
        }
        af[t][2] = r2;
    }

    // ---- MFMA: 21 tiles, B streamed from L2-resident prepacked frags ----
    floatx4 accR = {0, 0, 0, 0}, accO = {0, 0, 0, 0}, accC[5];
#pragma unroll
    for (int kc = 0; kc < 3; ++kc)
        accR = __builtin_amdgcn_mfma_f32_16x16x32_bf16(af[0][kc], wfrag[(0 * 3 + kc) * 64 + lane], accR, 0, 0, 0);
#pragma unroll
    for (int kc = 0; kc < 3; ++kc)
        accO = __builtin_amdgcn_mfma_f32_16x16x32_bf16(af[1][kc], wfrag[(1 * 3 + kc) * 64 + lane], accO, 0, 0, 0);
#pragma unroll
    for (int nt = 0; nt < 5; ++nt) {
        floatx4 a4 = {0, 0, 0, 0};
#pragma unroll
        for (int kc = 0; kc < 3; ++kc)
            a4 = __builtin_amdgcn_mfma_f32_16x16x32_bf16(af[2][kc], wfrag[((nt + 2) * 3 + kc) * 64 + lane], a4, 0, 0, 0);
        accC[nt] = a4;
    }

    // ---- decode, all register-parallel. D layout: col(=channel)=lane&15,
    // row(=position)=quad*4+i ----
    const int a_ = m >> 2, k_ = m & 3;          // box channel split (m<12)
    float anch;
    {   // anchor for (lvl, a_, k_ parity): w-anchor for k_==2, h-anchor for k_==3
        float e0, e1;
        if (lvl == 0) { e0 = a_ == 0 ? 12.64f  : a_ == 1 ? 37.88f  : 55.71f;
                        e1 = a_ == 0 ? 19.39f  : a_ == 1 ? 51.48f  : 138.31f; }
        else          { e0 = a_ == 0 ? 126.91f : a_ == 1 ? 131.57f : 279.92f;
                        e1 = a_ == 0 ? 78.23f  : a_ == 1 ? 214.55f : 258.87f; }
        anch = (k_ == 3) ? e1 : e0;
    }
    const float brg = b_reg[m < 12 ? m : 0];
    const float bob = b_obj[m < 3 ? m : 0];
    float bcl[5];
#pragma unroll
    for (int nt = 0; nt < 5; ++nt) bcl[nt] = b_cls[nt * 16 + m];

#pragma unroll
    for (int i = 0; i < 4; ++i) {
        const int prel = quad * 4 + i;
        const int pg   = pos0 + prel;
        const int gyi  = lvl ? (pg / 20) : (pg / 40);       // const-div magic
        const float gx = (float)(pg - gyi * W);
        const float gy = (float)gyi;

        if (m < 12) {           // box fields: each lane owns one (a,k) channel
            float sg = sigf(accR[i] + brg);
            float v;
            if (k_ == 0)      v = (sg * 2.0f - 0.5f + gx) * STRIDE;
            else if (k_ == 1) v = (sg * 2.0f - 0.5f + gy) * STRIDE;
            else { float t2 = sg * 2.0f; v = t2 * t2 * anch; }
            row[prel * RST + a_ * 5 + k_] = v;
        }
        if (m < 3)              // objectness
            row[prel * RST + m * 5 + 4] = sigf(accO[i] + bob);

        // cls: exp + 16-lane butterfly for the denom, scale BEFORE scatter
        float e[5];
        float s = 0.f;
#pragma unroll
        for (int nt = 0; nt < 5; ++nt) {
            // softmax shift-invariant; logits O(1), exp cannot overflow fp32
            e[nt] = __expf(accC[nt][i] + bcl[nt]);
            s += e[nt];
        }
        s += __shfl_xor(s, 1, 16);
        s += __shfl_xor(s, 2, 16);
        s += __shfl_xor(s, 4, 16);
        s += __shfl_xor(s, 8, 16);
        const float inv = __builtin_amdgcn_rcpf(s);
#pragma unroll
        for (int nt = 0; nt < 5; ++nt)
            row[prel * RST + 15 + nt * 16 + m] = e[nt] * inv;
    }
    __syncthreads();   // single-wave: ~free; orders ds_writes before writer reads

    // ---- writer: per-lane slot descriptors, plain copies, coalesced stores ----
    int wi0[4];
#pragma unroll
    for (int j = 0; j < 4; ++j) {
        int f = lane + 64 * j;
        int k = (f > 254) ? 0 : f;
        int a  = (k >= 85) + (k >= 170);
        int kk = k - a * 85;
        wi0[j] = (kk < 5) ? (a * 5 + kk) : (15 + (kk - 5));
    }
    float* outp = out + ((size_t)b * 510000 + LO * 85 + pos0 * 255);
    for (int p = 0; p < 16; ++p) {
        const float* rr = row + p * RST;
        float* po = outp + p * 255 + lane;
#pragma unroll
        for (int j = 0; j < 4; ++j) {
            if (!(lane == 63 && j == 3))            // f=255 masked
                po[64 * j] = rr[wi0[j]];
        }
    }
}

extern "C" void kernel_launch(void* const* d_in, const int* in_sizes, int n_in,
                              void* d_out, int out_size, void* d_ws, size_t ws_size,
                              hipStream_t stream) {
    (void)in_sizes; (void)n_in; (void)ws_size; (void)out_size;
    const float* fr0  = (const float*)d_in[0];
    const float* fo0  = (const float*)d_in[1];
    const float* fc0  = (const float*)d_in[2];
    const float* fr1  = (const float*)d_in[3];
    const float* fo1  = (const float*)d_in[4];
    const float* fc1  = (const float*)d_in[5];
    const float* wreg = (const float*)d_in[6];
    const float* breg = (const float*)d_in[7];
    const float* wobj = (const float*)d_in[8];
    const float* bobj = (const float*)d_in[9];
    const float* wcls = (const float*)d_in[10];
    const float* bcls = (const float*)d_in[11];
    float* out = (float*)d_out;
    short8* frags = (short8*)d_ws;    // 21*64*16 = 21504 B

    // d_ws is re-poisoned before every call -> rebuild fragments every call
    build_bfrags_kernel<<<6, 256, 0, stream>>>(wreg, wobj, wcls, frags);

    // 6400 level-0 + 1600 level-1 single-wave blocks
    yolo_head_kernel<<<8000, 64, 0, stream>>>(
        fr0, fo0, fc0, fr1, fo1, fc1,
        breg, bobj, bcls, frags, out);
}